// Round 1
// baseline (10073.061 us; speedup 1.0000x reference)
//
#include <hip/hip_runtime.h>
#include <hip/hip_bf16.h>
#include <math.h>

// RSSM scan, MI355X. Dims fixed by the reference:
// D=1024 Z=256 A=32 H=512 E=1024, T=64, B=512.
// Strategy: bf16 MFMA (16x16x32) 128x128-tile GEMM template, f32 accum.
// obs-contribution + prior branch hoisted out of the sequential scan.

using bf16 = __hip_bfloat16;
using short8 = __attribute__((ext_vector_type(8))) short;
using f32x4 = __attribute__((ext_vector_type(4))) float;

__device__ __forceinline__ float sp_f(float x) { return x > 15.f ? x : log1pf(__expf(x)); }
__device__ __forceinline__ float sg_f(float x) { return 1.f / (1.f + __expf(-x)); }

struct GArgs {
  const bf16* Ab;       // ASRC 0: A bf16 [M][K]
  const float* Af;      // ASRC 1: A f32 [M][K] (converted during staging)
  const bf16* Bw;       // weights bf16 [N][ldb] row-major (i.e. B^T)
  const float* bias;    // f32 [N] or null
  float* Cf;            // EPI 0 dest
  bf16* Cb;             // EPI 1/2 dest
  const float* addmat;  // EPI 2: f32 [M][ldadd] added before relu
  const float* s_src;   // ASRC 2 (sa stage): state [M][256]
  const float* nt_src;  // ASRC 2: per-row mask (null -> 1.0)
  const float* act_src; // ASRC 2: actions [M][32]
  int M, N, K, ldb, ldc, ldadd;
};

// 128x128 tile, BK=32, 256 threads = 4 waves, each wave a 64x64 quadrant
// (4x4 fragments of 16x16x32). C/D layout per m89: col=lane&15, row=4*(lane>>4)+r.
template<int ASRC, int EPI>
__device__ void gemm_core(const GArgs g, int bid) {
  __shared__ bf16 As[128 * 32];
  __shared__ bf16 Bs[128 * 32];
  const int ntiles = g.N >> 7;
  const int mt = bid / ntiles, nt = bid % ntiles;
  const int tid = threadIdx.x;
  const int l = tid & 63, w = tid >> 6;
  const int wm = w >> 1, wn = w & 1;
  const int l4r = l >> 2, l4b = l & 3;   // staging: 4 lanes x 16B per 64B row
  const int fl = l & 15, fg = l >> 4;    // fragment lane decomposition
  f32x4 acc[4][4] = {};

  for (int k0 = 0; k0 < g.K; k0 += 32) {
    // ---- stage A tile [128][32] ----
    if constexpr (ASRC == 0) {
#pragma unroll
      for (int i = 0; i < 2; ++i) {
        const int r = w * 32 + i * 16;
        const bf16* gp = g.Ab + (size_t)(mt * 128 + r + l4r) * g.K + k0 + l4b * 8;
        __builtin_amdgcn_global_load_lds((const __attribute__((address_space(1))) void*)gp,
                                         (__attribute__((address_space(3))) void*)(As + r * 32),
                                         16, 0, 0);
      }
    } else {
#pragma unroll
      for (int p = 0; p < 2; ++p) {
        const int e = p * 2048 + tid * 8;
        const int r = e >> 5, c = e & 31;
        const int rg = mt * 128 + r;
        float4 x0, x1;
        if constexpr (ASRC == 1) {
          const float* src = g.Af + (size_t)rg * g.K + k0 + c;
          x0 = *(const float4*)src; x1 = *(const float4*)(src + 4);
        } else {  // ASRC 2: [state*nt | action], K=288
          const int kg = k0 + c;
          if (kg < 256) {
            const float* src = g.s_src + rg * 256 + kg;
            x0 = *(const float4*)src; x1 = *(const float4*)(src + 4);
            const float ntv = g.nt_src ? g.nt_src[rg] : 1.f;
            x0.x *= ntv; x0.y *= ntv; x0.z *= ntv; x0.w *= ntv;
            x1.x *= ntv; x1.y *= ntv; x1.z *= ntv; x1.w *= ntv;
          } else {
            const float* src = g.act_src + rg * 32 + (kg - 256);
            x0 = *(const float4*)src; x1 = *(const float4*)(src + 4);
          }
        }
        bf16 tb[8] __attribute__((aligned(16)));
        tb[0] = __float2bfloat16(x0.x); tb[1] = __float2bfloat16(x0.y);
        tb[2] = __float2bfloat16(x0.z); tb[3] = __float2bfloat16(x0.w);
        tb[4] = __float2bfloat16(x1.x); tb[5] = __float2bfloat16(x1.y);
        tb[6] = __float2bfloat16(x1.z); tb[7] = __float2bfloat16(x1.w);
        *(short8*)(As + e) = *(const short8*)tb;
      }
    }
    // ---- stage B tile [128][32] (always bf16 weights) ----
#pragma unroll
    for (int i = 0; i < 2; ++i) {
      const int r = w * 32 + i * 16;
      const bf16* gp = g.Bw + (size_t)(nt * 128 + r + l4r) * g.ldb + k0 + l4b * 8;
      __builtin_amdgcn_global_load_lds((const __attribute__((address_space(1))) void*)gp,
                                       (__attribute__((address_space(3))) void*)(Bs + r * 32),
                                       16, 0, 0);
    }
    __syncthreads();
    // ---- compute ----
    short8 afr[4], bfr[4];
#pragma unroll
    for (int i = 0; i < 4; ++i)
      afr[i] = *(const short8*)(As + (wm * 64 + i * 16 + fl) * 32 + fg * 8);
#pragma unroll
    for (int i = 0; i < 4; ++i)
      bfr[i] = *(const short8*)(Bs + (wn * 64 + i * 16 + fl) * 32 + fg * 8);
#pragma unroll
    for (int mf = 0; mf < 4; ++mf)
#pragma unroll
      for (int nf = 0; nf < 4; ++nf)
        asm("v_mfma_f32_16x16x32_bf16 %0, %1, %2, %0"
            : "+v"(acc[mf][nf]) : "v"(afr[mf]), "v"(bfr[nf]));
    __syncthreads();
  }
  // ---- epilogue ----
#pragma unroll
  for (int mf = 0; mf < 4; ++mf) {
#pragma unroll
    for (int nf = 0; nf < 4; ++nf) {
      const int col = nt * 128 + wn * 64 + nf * 16 + fl;
      const float bv = g.bias ? g.bias[col] : 0.f;
#pragma unroll
      for (int r = 0; r < 4; ++r) {
        const int row = mt * 128 + wm * 64 + mf * 16 + fg * 4 + r;
        float v = acc[mf][nf][r] + bv;
        if constexpr (EPI == 2) v += g.addmat[(size_t)row * g.ldadd + col];
        if constexpr (EPI == 0) {
          g.Cf[(size_t)row * g.ldc + col] = v;
        } else {  // EPI 1/2: relu -> bf16
          v = v > 0.f ? v : 0.f;
          g.Cb[(size_t)row * g.ldc + col] = __float2bfloat16(v);
        }
      }
    }
  }
}

template<int ASRC, int EPI>
__global__ __launch_bounds__(256) void gemm_k(GArgs g) { gemm_core<ASRC, EPI>(g, blockIdx.x); }

__global__ __launch_bounds__(256) void gemm2_k(GArgs g0, GArgs g1, int nb0) {
  if ((int)blockIdx.x < nb0) gemm_core<0, 0>(g0, blockIdx.x);
  else                       gemm_core<0, 0>(g1, blockIdx.x - nb0);
}

// f32 -> bf16 conversion, 4 elems/thread
__global__ __launch_bounds__(256) void cvt_k(const float* __restrict__ src, bf16* __restrict__ dst, int n4) {
  int i = blockIdx.x * 256 + threadIdx.x;
  if (i >= n4) return;
  float4 v = ((const float4*)src)[i];
  bf16 t[4] __attribute__((aligned(8)));
  t[0] = __float2bfloat16(v.x); t[1] = __float2bfloat16(v.y);
  t[2] = __float2bfloat16(v.z); t[3] = __float2bfloat16(v.w);
  ((uint2*)dst)[i] = *(const uint2*)t;
}

// GRU gate math: rnn = (1-z)*tanh(i_n + r*h_n) + z*h
__global__ __launch_bounds__(256) void gates_k(const float* __restrict__ gi, const float* __restrict__ gh,
                                               const bf16* __restrict__ hprev, bf16* __restrict__ rnn) {
  int i = blockIdx.x * 256 + threadIdx.x;
  if (i >= 512 * 1024) return;
  int m = i >> 10, n = i & 1023;
  const float* gim = gi + (size_t)m * 3072;
  const float* ghm = gh + (size_t)m * 3072;
  float r = sg_f(gim[n] + ghm[n]);
  float z = sg_f(gim[1024 + n] + ghm[1024 + n]);
  float nn = tanhf(gim[2048 + n] + r * ghm[2048 + n]);
  float h = __bfloat162float(hprev[i]);
  rnn[i] = __float2bfloat16((1.f - z) * nn + z * h);
}

// belief = mean + (softplus(raw)+0.1)*noise ; write f32 out + bf16 carry
__global__ __launch_bounds__(256) void belief_k(const float* __restrict__ raw, const float* __restrict__ nb,
                                                float* __restrict__ obel, bf16* __restrict__ bbf) {
  int i = blockIdx.x * 256 + threadIdx.x;
  if (i >= 512 * 1024) return;
  int m = i >> 10, n = i & 1023;
  float mean = raw[(size_t)m * 2048 + n];
  float rs = raw[(size_t)m * 2048 + 1024 + n];
  float sd = sp_f(rs) + 0.1f;
  float b = mean + sd * nb[i];
  obel[i] = b;
  bbf[i] = __float2bfloat16(b);
}

// mean/std/state epilogue for prior & posterior heads: raw [rows][512] -> 3x [rows][256]
__global__ __launch_bounds__(256) void qpost_k(const float* __restrict__ raw, const float* __restrict__ noise,
                                               float* __restrict__ om, float* __restrict__ os,
                                               float* __restrict__ ost, int n) {
  int i = blockIdx.x * 256 + threadIdx.x;
  if (i >= n) return;
  int m = i >> 8, z = i & 255;
  float mean = raw[(size_t)m * 512 + z];
  float rs = raw[(size_t)m * 512 + 256 + z];
  float sd = sp_f(rs) + 0.1f;
  om[i] = mean; os[i] = sd; ost[i] = mean + sd * noise[i];
}

extern "C" void kernel_launch(void* const* d_in, const int* in_sizes, int n_in,
                              void* d_out, int out_size, void* d_ws, size_t ws_size,
                              hipStream_t stream) {
  const float* prev_state   = (const float*)d_in[0];
  const float* prev_belief  = (const float*)d_in[1];
  const float* actions      = (const float*)d_in[2];
  const float* observations = (const float*)d_in[3];
  const float* nonterm      = (const float*)d_in[4];
  const float* noise_belief = (const float*)d_in[5];
  const float* noise_prior  = (const float*)d_in[6];
  const float* noise_post   = (const float*)d_in[7];
  const float* W_sa  = (const float*)d_in[8];  const float* b_sa  = (const float*)d_in[9];
  const float* W_ih  = (const float*)d_in[10]; const float* b_ih  = (const float*)d_in[11];
  const float* W_hh  = (const float*)d_in[12]; const float* b_hh  = (const float*)d_in[13];
  const float* W_eb  = (const float*)d_in[14]; const float* b_eb  = (const float*)d_in[15];
  const float* W_bq  = (const float*)d_in[16]; const float* b_bq  = (const float*)d_in[17];
  const float* W_ebp = (const float*)d_in[18]; const float* b_ebp = (const float*)d_in[19];
  const float* W_sp  = (const float*)d_in[20]; const float* b_sp  = (const float*)d_in[21];
  const float* W_ebq = (const float*)d_in[22]; const float* b_ebq = (const float*)d_in[23];
  const float* W_sq  = (const float*)d_in[24]; const float* b_sq  = (const float*)d_in[25];

  float* out = (float*)d_out;
  const size_t off_bel = 0;
  const size_t off_pst = 33554432;   // p_state  [T*B][256]
  const size_t off_pm  = 41943040;   // p_mean
  const size_t off_psd = 50331648;   // p_std
  const size_t off_qst = 58720256;   // q_state
  const size_t off_qm  = 67108864;   // q_mean
  const size_t off_qsd = 75497472;   // q_std

  char* ws = (char*)d_ws;
  bf16* wbf   = (bf16*)ws;          // bf16 weight copies (elem offsets)
  bf16* w_sa  = wbf;                // [1024][288]
  bf16* w_ih  = wbf + 294912;       // [3072][1024]
  bf16* w_hh  = wbf + 3440640;      // [3072][1024]
  bf16* w_eb  = wbf + 6586368;      // [512][1024]
  bf16* w_bq  = wbf + 7110656;      // [2048][512]
  bf16* w_ebp = wbf + 8159232;      // [512][1024]
  bf16* w_sp  = wbf + 8683520;      // [512][512]
  bf16* w_ebq = wbf + 8945664;      // [512][2048]
  bf16* w_sq  = wbf + 9994240;      // [512][512]
  size_t p = 20971520;
  bf16* bel_bf   = (bf16*)(ws + p); p += 1048576;
  bf16* deter_bf = (bf16*)(ws + p); p += 1048576;
  bf16* rnn_bf   = (bf16*)(ws + p); p += 1048576;
  bf16* sh_bf    = (bf16*)(ws + p); p += 524288;
  bf16* shq_bf   = (bf16*)(ws + p); p += 524288;   // p = 25165824
  // p_raw (post-scan chunk buffer) aliases gi (dead post-scan) in the big path.
  float* p_raw = (float*)(ws + 25165824);
  float *gi, *gh, *bq_raw, *q_raw;
  if (ws_size >= 42991616ull) {
    gi     = (float*)(ws + 25165824);   // [512][3072]
    gh     = (float*)(ws + 31457280);   // [512][3072]
    bq_raw = (float*)(ws + 37748736);   // [512][2048]
    q_raw  = (float*)(ws + 41943040);   // [512][512]
  } else {
    // fallback: scan scratch lives in the p_state output region (dead during scan)
    float* scratch = out + off_pst;
    gi = scratch; gh = scratch + 1572864; bq_raw = gh + 1572864; q_raw = bq_raw + 1048576;
  }

  // ---- phase 0: weight conversion ----
  auto cvt = [&](const float* s, bf16* d, int n) {
    int n4 = n >> 2;
    cvt_k<<<(n4 + 255) / 256, 256, 0, stream>>>(s, d, n4);
  };
  cvt(W_sa, w_sa, 294912);   cvt(W_ih, w_ih, 3145728);  cvt(W_hh, w_hh, 3145728);
  cvt(W_eb, w_eb, 524288);   cvt(W_bq, w_bq, 1048576);  cvt(W_ebp, w_ebp, 524288);
  cvt(W_sp, w_sp, 262144);   cvt(W_ebq, w_ebq, 1048576); cvt(W_sq, w_sq, 262144);
  cvt(prev_belief, bel_bf, 524288);

  // ---- phase 1: hoisted obs contribution: obs @ W_ebq[:,1024:].T + b_ebq ----
  float* obs_c = out + off_pm;  // [32768][512] f32, spans p_mean+p_std (dead during scan)
  {
    GArgs g{}; g.Af = observations; g.Bw = w_ebq + 1024; g.ldb = 2048; g.bias = b_ebq;
    g.Cf = obs_c; g.ldc = 512; g.M = 32768; g.N = 512; g.K = 1024;
    gemm_k<1, 0><<<1024, 256, 0, stream>>>(g);
  }

  // ---- phase 2: sequential scan ----
  for (int t = 0; t < 64; ++t) {
    { // sa: deter = relu([s*nt | a] @ W_sa.T + b_sa)
      GArgs g{};
      g.s_src  = (t == 0) ? prev_state : out + off_qst + (size_t)(t - 1) * 131072;
      g.nt_src = (t == 0) ? nullptr : nonterm + (size_t)(t - 1) * 512;
      g.act_src = actions + (size_t)t * 16384;
      g.Bw = w_sa; g.ldb = 288; g.bias = b_sa; g.Cb = deter_bf; g.ldc = 1024;
      g.M = 512; g.N = 1024; g.K = 288;
      gemm_k<2, 1><<<32, 256, 0, stream>>>(g);
    }
    { // gi = deter @ W_ih.T + b_ih ; gh = belief @ W_hh.T + b_hh (one launch)
      GArgs g0{}; g0.Ab = deter_bf; g0.Bw = w_ih; g0.ldb = 1024; g0.bias = b_ih;
      g0.Cf = gi; g0.ldc = 3072; g0.M = 512; g0.N = 3072; g0.K = 1024;
      GArgs g1 = g0; g1.Ab = bel_bf; g1.Bw = w_hh; g1.bias = b_hh; g1.Cf = gh;
      gemm2_k<<<192, 256, 0, stream>>>(g0, g1, 96);
    }
    gates_k<<<2048, 256, 0, stream>>>(gi, gh, bel_bf, rnn_bf);
    { // sh = relu(rnn @ W_eb.T + b_eb)
      GArgs g{}; g.Ab = rnn_bf; g.Bw = w_eb; g.ldb = 1024; g.bias = b_eb;
      g.Cb = sh_bf; g.ldc = 512; g.M = 512; g.N = 512; g.K = 1024;
      gemm_k<0, 1><<<16, 256, 0, stream>>>(g);
    }
    { // bq_raw = sh @ W_bq.T + b_bq  [512][2048]
      GArgs g{}; g.Ab = sh_bf; g.Bw = w_bq; g.ldb = 512; g.bias = b_bq;
      g.Cf = bq_raw; g.ldc = 2048; g.M = 512; g.N = 2048; g.K = 512;
      gemm_k<0, 0><<<64, 256, 0, stream>>>(g);
    }
    belief_k<<<2048, 256, 0, stream>>>(bq_raw, noise_belief + (size_t)t * 524288,
                                       out + off_bel + (size_t)t * 524288, bel_bf);
    { // shq = relu(belief @ W_ebq[:,:1024].T + obs_c[t])
      GArgs g{}; g.Ab = bel_bf; g.Bw = w_ebq; g.ldb = 2048;
      g.addmat = obs_c + (size_t)t * 262144; g.ldadd = 512;
      g.Cb = shq_bf; g.ldc = 512; g.M = 512; g.N = 512; g.K = 1024;
      gemm_k<0, 2><<<16, 256, 0, stream>>>(g);
    }
    { // q_raw = shq @ W_sq.T + b_sq
      GArgs g{}; g.Ab = shq_bf; g.Bw = w_sq; g.ldb = 512; g.bias = b_sq;
      g.Cf = q_raw; g.ldc = 512; g.M = 512; g.N = 512; g.K = 512;
      gemm_k<0, 0><<<16, 256, 0, stream>>>(g);
    }
    qpost_k<<<512, 256, 0, stream>>>(q_raw, noise_post + (size_t)t * 131072,
                                     out + off_qm + (size_t)t * 131072,
                                     out + off_qsd + (size_t)t * 131072,
                                     out + off_qst + (size_t)t * 131072, 131072);
  }

  // ---- phase 3: prior branch (depends only on beliefs) ----
  bf16* shp = (bf16*)(out + off_pst);  // [32768][512] bf16, exactly fills p_state region
  {
    GArgs g{}; g.Af = out + off_bel; g.Bw = w_ebp; g.ldb = 1024; g.bias = b_ebp;
    g.Cb = shp; g.ldc = 512; g.M = 32768; g.N = 512; g.K = 1024;
    gemm_k<1, 1><<<1024, 256, 0, stream>>>(g);
  }
  for (int c = 0; c < 16; ++c) {  // 2048-row chunks: GEMM -> p_raw, then epilogue
    {
      GArgs g{}; g.Ab = shp + (size_t)c * 1048576; g.Bw = w_sp; g.ldb = 512; g.bias = b_sp;
      g.Cf = p_raw; g.ldc = 512; g.M = 2048; g.N = 512; g.K = 512;
      gemm_k<0, 0><<<64, 256, 0, stream>>>(g);
    }
    qpost_k<<<2048, 256, 0, stream>>>(p_raw, noise_prior + (size_t)c * 524288,
                                      out + off_pm + (size_t)c * 524288,
                                      out + off_psd + (size_t)c * 524288,
                                      out + off_pst + (size_t)c * 524288, 524288);
  }
}